// Round 4
// baseline (729.651 us; speedup 1.0000x reference)
//
#include <hip/hip_runtime.h>
#include <hip/hip_fp16.h>

#define L_ 13
#define B_ 32
#define S_ 128
#define H_ 768
#define NU 32
#define GG 64
#define TU 96
#define LN_EPS 1e-3f
#define SEQ_ST 68     // seq LDS row stride (floats)
#define XP_ST 100     // xp LDS row stride (floats)
#define XT_ST 129     // xT2 row stride (half2 units) — odd => conflict-free columns

typedef float v2f __attribute__((ext_vector_type(2)));

__device__ __forceinline__ float sigmoidf_(float a) { return 1.0f / (1.0f + __expf(-a)); }
__device__ __forceinline__ float tanhf_(float a) { float e = __expf(-2.0f * a); return (1.0f - e) / (1.0f + e); }
__device__ __forceinline__ void pkfma(v2f& a, v2f x, v2f w) {
    asm("v_pk_fma_f32 %0, %1, %2, %0" : "+v"(a) : "v"(x), "v"(w));
}

// ---------------- lin_all = xs @ W_lin + b_lin for ALL 13 layers (fully parallel) ----------------
__global__ __launch_bounds__(256) void lin_kernel(
    const float* __restrict__ xs, const float* __restrict__ Wl,
    const float* __restrict__ bl, float* __restrict__ lin)
{
    __shared__ float sA[64][68];
    __shared__ float sW[64][68];
    const int t = threadIdx.x;
    const size_t row0 = (size_t)blockIdx.x * 64;
    const int r4 = (t >> 4) << 2;
    const int c4 = (t & 15) << 2;

    float acc[4][4];
    #pragma unroll
    for (int i = 0; i < 4; ++i)
        #pragma unroll
        for (int j = 0; j < 4; ++j) acc[i][j] = 0.f;

    for (int kt = 0; kt < H_; kt += 64) {
        #pragma unroll
        for (int p = 0; p < 4; ++p) {
            int idx = t + 256 * p;
            int r = idx >> 4, cc = (idx & 15) << 2;
            *(float4*)&sA[r][cc] = *(const float4*)&xs[(row0 + r) * H_ + kt + cc];
            *(float4*)&sW[r][cc] = *(const float4*)&Wl[(size_t)(kt + r) * GG + cc];
        }
        __syncthreads();
        #pragma unroll 8
        for (int k = 0; k < 64; ++k) {
            float a0 = sA[r4 + 0][k], a1 = sA[r4 + 1][k], a2 = sA[r4 + 2][k], a3 = sA[r4 + 3][k];
            float4 w = *(const float4*)&sW[k][c4];
            acc[0][0] += a0 * w.x; acc[0][1] += a0 * w.y; acc[0][2] += a0 * w.z; acc[0][3] += a0 * w.w;
            acc[1][0] += a1 * w.x; acc[1][1] += a1 * w.y; acc[1][2] += a1 * w.z; acc[1][3] += a1 * w.w;
            acc[2][0] += a2 * w.x; acc[2][1] += a2 * w.y; acc[2][2] += a2 * w.z; acc[2][3] += a2 * w.w;
            acc[3][0] += a3 * w.x; acc[3][1] += a3 * w.y; acc[3][2] += a3 * w.z; acc[3][3] += a3 * w.w;
        }
        __syncthreads();
    }
    float4 bv = *(const float4*)&bl[c4];
    #pragma unroll
    for (int i = 0; i < 4; ++i) {
        float4 o = make_float4(acc[i][0] + bv.x, acc[i][1] + bv.y, acc[i][2] + bv.z, acc[i][3] + bv.w);
        *(float4*)&lin[(row0 + r4 + i) * GG + c4] = o;
    }
}

// ---------------- one block per batch: 13 x (LN + xp + bidir GRU scan) + classifier ----------------
__global__ __launch_bounds__(512) void chain_kernel(
    const float* __restrict__ lin_all,
    const float* __restrict__ Wr_f, const float* __restrict__ b_f,
    const float* __restrict__ Wr_b, const float* __restrict__ b_b,
    const float* __restrict__ Wk_f, const float* __restrict__ Wk_b,
    const float* __restrict__ ln_g, const float* __restrict__ ln_b,
    const float* __restrict__ W_cls, const float* __restrict__ b_cls,
    float* __restrict__ out)
{
    extern __shared__ float sm[];
    float*   seqb = sm;                          // [128][SEQ_ST]  GRU outputs only
    __half2* xt2  = (__half2*)(sm + S_ * SEQ_ST);// [32][XT_ST]    x transposed, fp16 pairs of k
    float*   xpf  = sm + S_ * SEQ_ST + 32 * XT_ST * 1;  // half2 == 1 float slot
    // (xt2 occupies 32*XT_ST float-slots)
    float*   xpb  = xpf + S_ * XP_ST;
    float*   hbf  = xpb + S_ * XP_ST;
    float*   hbb  = hbf + NU;

    const int b = blockIdx.x;
    const int t = threadIdx.x;
    const int wave = t >> 6;
    const int lane = t & 63;
    const int u = lane & 31;
    const int half = lane >> 5;

    for (int i = t; i < S_ * SEQ_ST; i += 512) seqb[i] = 0.f;

    // ---- scan-wave persistent state (waves 0=fwd, 1=bwd) ----
    v2f wz2[8], wr2[8], wh2[8], h2r[8];
    float h_own = 0.f, rbz = 0.f, rbr = 0.f, rbh = 0.f;
    if (wave < 2) {
        const float* Wr   = wave ? Wr_b : Wr_f;
        const float* bias = wave ? b_b  : b_f;
        #pragma unroll
        for (int jj = 0; jj < 8; ++jj) {
            int j = half * 16 + 2 * jj;
            wz2[jj] = v2f{ Wr[j * TU + u],          Wr[(j + 1) * TU + u] };
            wr2[jj] = v2f{ Wr[j * TU + NU + u],     Wr[(j + 1) * TU + NU + u] };
            wh2[jj] = v2f{ Wr[j * TU + 2 * NU + u], Wr[(j + 1) * TU + 2 * NU + u] };
            h2r[jj] = v2f{ 0.f, 0.f };
        }
        rbz = bias[TU + u]; rbr = bias[TU + NU + u]; rbh = bias[TU + 2 * NU + u];
    }

    // phase-1 mapping
    const int g = t >> 4;
    const int c16 = t & 15;
    const int c4 = c16 << 2;
    // phase-2 mapping
    const int rgrp = t & 31;
    const int cg = t >> 5;
    const int dsel = cg >> 3;
    const int cc = (cg & 7) * 12;
    const float* WkX   = dsel ? Wk_b : Wk_f;
    const float* bias0 = dsel ? b_b  : b_f;
    float* xpX = dsel ? xpb : xpf;

    __syncthreads();

    for (int l = 0; l < L_; ++l) {
        const float* linb = lin_all + ((size_t)(l * B_ + b) * S_) * GG;

        // ---- phase 1: x = LN(lin + seq) -> write fp16-transposed into xt2 ----
        #pragma unroll
        for (int p = 0; p < 4; ++p) {
            const int r = g + 32 * p;
            float4 lv = *(const float4*)&linb[(size_t)r * GG + c4];
            float4 sv = *(const float4*)&seqb[r * SEQ_ST + c4];
            float v0 = lv.x + sv.x, v1 = lv.y + sv.y, v2 = lv.z + sv.z, v3 = lv.w + sv.w;
            float s = v0 + v1 + v2 + v3;
            #pragma unroll
            for (int off = 1; off < 16; off <<= 1) s += __shfl_xor(s, off);
            const float mean = s * 0.015625f;
            const float d0 = v0 - mean, d1 = v1 - mean, d2 = v2 - mean, d3 = v3 - mean;
            float q = d0 * d0 + d1 * d1 + d2 * d2 + d3 * d3;
            #pragma unroll
            for (int off = 1; off < 16; off <<= 1) q += __shfl_xor(q, off);
            const float rstd = rsqrtf(q * 0.015625f + LN_EPS);
            float4 gm = *(const float4*)&ln_g[c4];
            float4 bt = *(const float4*)&ln_b[c4];
            const float x0 = d0 * rstd * gm.x + bt.x;
            const float x1 = d1 * rstd * gm.y + bt.y;
            const float x2 = d2 * rstd * gm.z + bt.z;
            const float x3 = d3 * rstd * gm.w + bt.w;
            xt2[(2 * c16 + 0) * XT_ST + r] = __floats2half2_rn(x0, x1);
            xt2[(2 * c16 + 1) * XT_ST + r] = __floats2half2_rn(x2, x3);
        }
        __syncthreads();

        // ---- phase 2: xp = x @ Wk + bias0 (fp16 x from transposed LDS, conflict-free) ----
        {
            v2f acc[4][6];
            #pragma unroll
            for (int m = 0; m < 6; ++m) {
                v2f bi = v2f{ bias0[cc + 2 * m], bias0[cc + 2 * m + 1] };
                acc[0][m] = bi; acc[1][m] = bi; acc[2][m] = bi; acc[3][m] = bi;
            }
            #pragma unroll 4
            for (int k2 = 0; k2 < 32; ++k2) {
                const int k0 = 2 * k2, k1 = 2 * k2 + 1;
                __half2 h0 = xt2[k2 * XT_ST + rgrp];
                __half2 h1 = xt2[k2 * XT_ST + rgrp + 32];
                __half2 h2 = xt2[k2 * XT_ST + rgrp + 64];
                __half2 h3 = xt2[k2 * XT_ST + rgrp + 96];
                float4 wA0 = *(const float4*)&WkX[k0 * TU + cc];
                float4 wB0 = *(const float4*)&WkX[k0 * TU + cc + 4];
                float4 wC0 = *(const float4*)&WkX[k0 * TU + cc + 8];
                float4 wA1 = *(const float4*)&WkX[k1 * TU + cc];
                float4 wB1 = *(const float4*)&WkX[k1 * TU + cc + 4];
                float4 wC1 = *(const float4*)&WkX[k1 * TU + cc + 8];
                v2f w00 = v2f{wA0.x, wA0.y}, w01 = v2f{wA0.z, wA0.w};
                v2f w02 = v2f{wB0.x, wB0.y}, w03 = v2f{wB0.z, wB0.w};
                v2f w04 = v2f{wC0.x, wC0.y}, w05 = v2f{wC0.z, wC0.w};
                v2f w10 = v2f{wA1.x, wA1.y}, w11 = v2f{wA1.z, wA1.w};
                v2f w12 = v2f{wB1.x, wB1.y}, w13 = v2f{wB1.z, wB1.w};
                v2f w14 = v2f{wC1.x, wC1.y}, w15 = v2f{wC1.z, wC1.w};
                float xa, xb; v2f xx;
                xa = __low2float(h0); xb = __high2float(h0);
                xx = v2f{xa, xa};
                pkfma(acc[0][0], xx, w00); pkfma(acc[0][1], xx, w01); pkfma(acc[0][2], xx, w02);
                pkfma(acc[0][3], xx, w03); pkfma(acc[0][4], xx, w04); pkfma(acc[0][5], xx, w05);
                xx = v2f{xb, xb};
                pkfma(acc[0][0], xx, w10); pkfma(acc[0][1], xx, w11); pkfma(acc[0][2], xx, w12);
                pkfma(acc[0][3], xx, w13); pkfma(acc[0][4], xx, w14); pkfma(acc[0][5], xx, w15);
                xa = __low2float(h1); xb = __high2float(h1);
                xx = v2f{xa, xa};
                pkfma(acc[1][0], xx, w00); pkfma(acc[1][1], xx, w01); pkfma(acc[1][2], xx, w02);
                pkfma(acc[1][3], xx, w03); pkfma(acc[1][4], xx, w04); pkfma(acc[1][5], xx, w05);
                xx = v2f{xb, xb};
                pkfma(acc[1][0], xx, w10); pkfma(acc[1][1], xx, w11); pkfma(acc[1][2], xx, w12);
                pkfma(acc[1][3], xx, w13); pkfma(acc[1][4], xx, w14); pkfma(acc[1][5], xx, w15);
                xa = __low2float(h2); xb = __high2float(h2);
                xx = v2f{xa, xa};
                pkfma(acc[2][0], xx, w00); pkfma(acc[2][1], xx, w01); pkfma(acc[2][2], xx, w02);
                pkfma(acc[2][3], xx, w03); pkfma(acc[2][4], xx, w04); pkfma(acc[2][5], xx, w05);
                xx = v2f{xb, xb};
                pkfma(acc[2][0], xx, w10); pkfma(acc[2][1], xx, w11); pkfma(acc[2][2], xx, w12);
                pkfma(acc[2][3], xx, w13); pkfma(acc[2][4], xx, w14); pkfma(acc[2][5], xx, w15);
                xa = __low2float(h3); xb = __high2float(h3);
                xx = v2f{xa, xa};
                pkfma(acc[3][0], xx, w00); pkfma(acc[3][1], xx, w01); pkfma(acc[3][2], xx, w02);
                pkfma(acc[3][3], xx, w03); pkfma(acc[3][4], xx, w04); pkfma(acc[3][5], xx, w05);
                xx = v2f{xb, xb};
                pkfma(acc[3][0], xx, w10); pkfma(acc[3][1], xx, w11); pkfma(acc[3][2], xx, w12);
                pkfma(acc[3][3], xx, w13); pkfma(acc[3][4], xx, w14); pkfma(acc[3][5], xx, w15);
            }
            #pragma unroll
            for (int i = 0; i < 4; ++i) {
                const int r = rgrp + 32 * i;
                *(float4*)&xpX[r * XP_ST + cc]     = make_float4(acc[i][0].x, acc[i][0].y, acc[i][1].x, acc[i][1].y);
                *(float4*)&xpX[r * XP_ST + cc + 4] = make_float4(acc[i][2].x, acc[i][2].y, acc[i][3].x, acc[i][3].y);
                *(float4*)&xpX[r * XP_ST + cc + 8] = make_float4(acc[i][4].x, acc[i][4].y, acc[i][5].x, acc[i][5].y);
            }
        }
        __syncthreads();

        // ---- phase 3: fwd (wave 0) and bwd (wave 1) scans, concurrent on separate SIMDs ----
        if (wave < 2) {
            const int dir = wave;
            const float* xp = dir ? xpb : xpf;
            float* hb = dir ? hbb : hbf;
            int s = dir ? (S_ - 1) : 0;
            const int stp = dir ? -1 : 1;
            float xz = xp[s * XP_ST + u], xr = xp[s * XP_ST + NU + u], xh = xp[s * XP_ST + 2 * NU + u];
            for (int st = 0; st < S_; ++st) {
                float nz = 0.f, nr = 0.f, nh = 0.f;
                if (st < S_ - 1) {
                    const int sn = s + stp;
                    nz = xp[sn * XP_ST + u]; nr = xp[sn * XP_ST + NU + u]; nh = xp[sn * XP_ST + 2 * NU + u];
                }
                v2f az = v2f{0.f, 0.f}, ar = v2f{0.f, 0.f}, ah = v2f{0.f, 0.f};
                #pragma unroll
                for (int jj = 0; jj < 8; ++jj) {
                    pkfma(az, h2r[jj], wz2[jj]);
                    pkfma(ar, h2r[jj], wr2[jj]);
                    pkfma(ah, h2r[jj], wh2[jj]);
                }
                float rz = az.x + az.y, rr = ar.x + ar.y, rh = ah.x + ah.y;
                rz += __shfl_xor(rz, 32);
                rr += __shfl_xor(rr, 32);
                rh += __shfl_xor(rh, 32);
                const float z  = sigmoidf_(xz + rz + rbz);
                const float r  = sigmoidf_(xr + rr + rbr);
                const float hh = tanhf_(xh + r * (rh + rbh));
                const float hn = hh + z * (h_own - hh);
                hb[u] = hn;
                seqb[s * SEQ_ST + dir * NU + u] = hn;
                const float4* hbp = (const float4*)(hb + half * 16);
                #pragma unroll
                for (int i = 0; i < 4; ++i) {
                    float4 f = hbp[i];
                    h2r[2 * i]     = v2f{f.x, f.y};
                    h2r[2 * i + 1] = v2f{f.z, f.w};
                }
                h_own = hn;
                s += stp; xz = nz; xr = nr; xh = nh;
            }
        }
        __syncthreads();
    }

    // ---- classifier ----
    if (t == 0) {
        float l0 = b_cls[0], l1 = b_cls[1];
        for (int j = 0; j < NU; ++j) {
            const float hf = hbf[j], hk = hbb[j];
            l0 += hf * W_cls[4 * j]     + hk * W_cls[4 * j + 2];
            l1 += hf * W_cls[4 * j + 1] + hk * W_cls[4 * j + 3];
        }
        const float m = fmaxf(l0, l1);
        const float e0 = __expf(l0 - m), e1 = __expf(l1 - m);
        const float inv = 1.0f / (e0 + e1);
        out[b * 2 + 0] = e0 * inv;
        out[b * 2 + 1] = e1 * inv;
    }
}

extern "C" void kernel_launch(void* const* d_in, const int* in_sizes, int n_in,
                              void* d_out, int out_size, void* d_ws, size_t ws_size,
                              hipStream_t stream) {
    const float* xs    = (const float*)d_in[0];
    const float* W_lin = (const float*)d_in[1];
    const float* b_lin = (const float*)d_in[2];
    const float* ln_g  = (const float*)d_in[3];
    const float* ln_b  = (const float*)d_in[4];
    const float* Wk_f  = (const float*)d_in[5];
    const float* Wr_f  = (const float*)d_in[6];
    const float* b_f   = (const float*)d_in[7];
    const float* Wk_b  = (const float*)d_in[8];
    const float* Wr_b  = (const float*)d_in[9];
    const float* b_b   = (const float*)d_in[10];
    const float* W_cls = (const float*)d_in[11];
    const float* b_cls = (const float*)d_in[12];
    float* out = (float*)d_out;

    float* lin_all = (float*)d_ws;   // 13*4096*64 f32 = 13,631,488 B

    const int smem = (S_ * SEQ_ST + 32 * XT_ST + 2 * S_ * XP_ST + 64) * (int)sizeof(float); // 153,984 B
    (void)hipFuncSetAttribute((const void*)chain_kernel,
                              hipFuncAttributeMaxDynamicSharedMemorySize, smem);

    lin_kernel<<<(L_ * B_ * S_) / 64, 256, 0, stream>>>(xs, W_lin, b_lin, lin_all);

    chain_kernel<<<B_, 512, smem, stream>>>(
        lin_all, Wr_f, b_f, Wr_b, b_b, Wk_f, Wk_b, ln_g, ln_b, W_cls, b_cls, out);
}